// Round 2
// baseline (99.515 us; speedup 1.0000x reference)
//
#include <hip/hip_runtime.h>

#define NB      256
#define NP1     10000
#define KNN     32
#define THREADS 1024
#define NWAVES  (THREADS / 64)
#define ITEMS   10            // ceil(NP1 / THREADS)
#define NEG_INF -1000000000.0f

__global__ __launch_bounds__(THREADS) void hybrid_scoring_kernel(
    const float* __restrict__ query,        // [B,2]
    const float* __restrict__ psi,          // [B,NP1,2]
    const int*   __restrict__ knn,          // [B,NP1,K]
    const int*   __restrict__ mask,         // [B,NP1] (bool pushed as int32)
    const float* __restrict__ cur,          // [B,2]
    const float* __restrict__ allc,         // [B,NP1,2]
    const float* __restrict__ lam_p,        // [1]
    const float* __restrict__ mu_p,         // [1]
    float* __restrict__ out)                // [B,NP1]
{
    __shared__ unsigned s_psi[NP1];         // packed bf16 (y<<16 | x), ~40 KB
    __shared__ float red_m[NWAVES], red_s[NWAVES];
    __shared__ float s_lse;

    const int b = blockIdx.x;
    const int t = threadIdx.x;

    const float lam = lam_p[0];
    const float mu  = mu_p[0];
    const float qx  = query[2*b],  qy = query[2*b+1];
    const float cx  = cur[2*b],    cy = cur[2*b+1];

    const float2* __restrict__ pb = (const float2*)(psi  + (long)b * NP1 * 2);
    const float2* __restrict__ ab = (const float2*)(allc + (long)b * NP1 * 2);
    const int4*   __restrict__ kb = (const int4*)(knn + (long)b * NP1 * KNN);
    const int*    __restrict__ mb = mask + (long)b * NP1;

    // ---- stage psi[b] into LDS as packed bf16 pairs; keep own embedding in regs
    float2 pown[ITEMS];
    #pragma unroll
    for (int i = 0; i < ITEMS; ++i) {
        const int n = t + i * THREADS;
        float2 p = make_float2(0.f, 0.f);
        if (n < NP1) {
            p = pb[n];
            unsigned ux = __float_as_uint(p.x);
            unsigned uy = __float_as_uint(p.y);
            ux = (ux + 0x7FFFu + ((ux >> 16) & 1u)) >> 16;          // bf16 RNE, low half
            uy = (uy + 0x7FFFu + ((uy >> 16) & 1u)) & 0xFFFF0000u;  // bf16 RNE, high half
            s_psi[n] = uy | ux;
        }
        pown[i] = p;
    }
    __syncthreads();

    // ---- scores + online logsumexp
    float sc[ITEMS];
    float m = -INFINITY, s = 0.0f;

    #pragma unroll
    for (int i = 0; i < ITEMS; ++i) {
        const int n = t + i * THREADS;
        float v = 0.0f;
        if (n < NP1) {
            float nsx = 0.f, nsy = 0.f;
            const int4* kp = kb + n * (KNN / 4);
            #pragma unroll
            for (int j = 0; j < KNN / 4; ++j) {
                const int4 id = kp[j];
                const unsigned u0 = s_psi[id.x];
                const unsigned u1 = s_psi[id.y];
                const unsigned u2 = s_psi[id.z];
                const unsigned u3 = s_psi[id.w];
                nsx += __uint_as_float(u0 << 16) + __uint_as_float(u1 << 16)
                     + __uint_as_float(u2 << 16) + __uint_as_float(u3 << 16);
                nsy += __uint_as_float(u0 & 0xFFFF0000u) + __uint_as_float(u1 & 0xFFFF0000u)
                     + __uint_as_float(u2 & 0xFFFF0000u) + __uint_as_float(u3 & 0xFFFF0000u);
            }
            const float2 p  = pown[i];
            const float2 ac = ab[n];
            const float dx = ac.x - cx, dy = ac.y - cy;
            const float dist = sqrtf(dx * dx + dy * dy);
            v = p.x * qx + p.y * qy + lam * (p.x * nsx + p.y * nsy) - mu * dist;
            if (mb[n] != 0) v = NEG_INF;
            const float nm = fmaxf(m, v);
            s = s * __expf(m - nm) + __expf(v - nm);
            m = nm;
        }
        sc[i] = v;
    }

    // ---- wave reduce (m, s)
    #pragma unroll
    for (int off = 32; off > 0; off >>= 1) {
        const float om = __shfl_down(m, off);
        const float os = __shfl_down(s, off);
        const float nm = fmaxf(m, om);
        s = s * __expf(m - nm) + os * __expf(om - nm);
        m = nm;
    }
    const int wid = t >> 6, lane = t & 63;
    if (lane == 0) { red_m[wid] = m; red_s[wid] = s; }
    __syncthreads();
    if (t == 0) {
        float M = red_m[0], S = red_s[0];
        for (int w = 1; w < NWAVES; ++w) {
            const float nm = fmaxf(M, red_m[w]);
            S = S * __expf(M - nm) + red_s[w] * __expf(red_m[w] - nm);
            M = nm;
        }
        s_lse = M + logf(S);
    }
    __syncthreads();
    const float lse = s_lse;

    // ---- write log-softmax
    #pragma unroll
    for (int i = 0; i < ITEMS; ++i) {
        const int n = t + i * THREADS;
        if (n < NP1) out[(long)b * NP1 + n] = sc[i] - lse;
    }
}

extern "C" void kernel_launch(void* const* d_in, const int* in_sizes, int n_in,
                              void* d_out, int out_size, void* d_ws, size_t ws_size,
                              hipStream_t stream) {
    const float* query = (const float*)d_in[0];
    const float* psi   = (const float*)d_in[1];
    const int*   knn   = (const int*)d_in[2];
    const int*   mask  = (const int*)d_in[3];
    const float* cur   = (const float*)d_in[4];
    const float* allc  = (const float*)d_in[5];
    const float* lam   = (const float*)d_in[6];
    const float* mu    = (const float*)d_in[7];
    float* out = (float*)d_out;

    hybrid_scoring_kernel<<<NB, THREADS, 0, stream>>>(
        query, psi, knn, mask, cur, allc, lam, mu, out);
}